// Round 1
// baseline (794.244 us; speedup 1.0000x reference)
//
#include <hip/hip_runtime.h>
#include <math.h>

typedef unsigned short u16t;
typedef unsigned int   u32t;
typedef __bf16 bf16x8 __attribute__((ext_vector_type(8)));
typedef float  f32x4  __attribute__((ext_vector_type(4)));

#define DEV static __device__ __forceinline__

DEV u16t bfc(float x){ u32t b=__float_as_uint(x); b += 0x7FFFu + ((b>>16)&1u); return (u16t)(b>>16); }
DEV float flc(u16t u){ return __uint_as_float(((u32t)u)<<16); }
DEV u32t pk2(u16t a, u16t b){ return (u32t)a | ((u32t)b<<16); }
DEV f32x4 fz4(){ f32x4 z = {0.f,0.f,0.f,0.f}; return z; }
DEV bf16x8 bz8(){ uint4 z = make_uint4(0u,0u,0u,0u); return __builtin_bit_cast(bf16x8, z); }
DEV f32x4 MFMA(bf16x8 a, bf16x8 b, f32x4 c){ return __builtin_amdgcn_mfma_f32_16x16x32_bf16(a,b,c,0,0,0); }
DEV void unpack8(uint4 u, float* o){
  o[0]=flc((u16t)(u.x&0xffffu)); o[1]=flc((u16t)(u.x>>16));
  o[2]=flc((u16t)(u.y&0xffffu)); o[3]=flc((u16t)(u.y>>16));
  o[4]=flc((u16t)(u.z&0xffffu)); o[5]=flc((u16t)(u.z>>16));
  o[6]=flc((u16t)(u.w&0xffffu)); o[7]=flc((u16t)(u.w>>16));
}

// ---------------- weight transpose: out[n][k] = bf16(in[k][n]) ----------------
__global__ void kwT(const float* __restrict__ in, u16t* __restrict__ out, int N, int K){
  int tid = blockIdx.x*blockDim.x + threadIdx.x;
  if (tid >= N*K) return;
  int n = tid / K, k = tid - n*K;
  out[tid] = bfc(in[(size_t)k*N + n]);
}

// ---------------- LayerNorm over 512-wide rows -> bf16 ----------------
__global__ __launch_bounds__(256) void kln(const float* __restrict__ in, const float* __restrict__ g,
                                           const float* __restrict__ b, u16t* __restrict__ out){
  int wv = threadIdx.x >> 6, lane = threadIdx.x & 63;
  int row = blockIdx.x*4 + wv;
  const float4* rp = reinterpret_cast<const float4*>(in + (size_t)row*512);
  float4 v0 = rp[lane], v1 = rp[lane+64];
  float s = v0.x+v0.y+v0.z+v0.w + v1.x+v1.y+v1.z+v1.w;
  float q = v0.x*v0.x+v0.y*v0.y+v0.z*v0.z+v0.w*v0.w + v1.x*v1.x+v1.y*v1.y+v1.z*v1.z+v1.w*v1.w;
  #pragma unroll
  for (int m=1;m<64;m<<=1){ s += __shfl_xor(s,m); q += __shfl_xor(q,m); }
  float mean = s*(1.f/512.f), var = q*(1.f/512.f)-mean*mean, rs = rsqrtf(var+1e-5f);
  const float4* gp = reinterpret_cast<const float4*>(g);
  const float4* bp = reinterpret_cast<const float4*>(b);
  float4 g0=gp[lane], g1=gp[lane+64], b0=bp[lane], b1=bp[lane+64];
  u16t* op = out + (size_t)row*512;
  ushort4 o0 = make_ushort4(bfc((v0.x-mean)*rs*g0.x+b0.x), bfc((v0.y-mean)*rs*g0.y+b0.y),
                            bfc((v0.z-mean)*rs*g0.z+b0.z), bfc((v0.w-mean)*rs*g0.w+b0.w));
  ushort4 o1 = make_ushort4(bfc((v1.x-mean)*rs*g1.x+b1.x), bfc((v1.y-mean)*rs*g1.y+b1.y),
                            bfc((v1.z-mean)*rs*g1.z+b1.z), bfc((v1.w-mean)*rs*g1.w+b1.w));
  reinterpret_cast<ushort4*>(op)[lane]    = o0;
  reinterpret_cast<ushort4*>(op)[lane+64] = o1;
}

// ---------------- QKV GEMM: hln[2048][512] @ WtQKV^T -> Q/K [b][h][l][d], V^T [b][h][d][m] ----------------
__global__ __launch_bounds__(256) void kqkv(const u16t* __restrict__ hln, const u16t* __restrict__ Wt,
    const float* __restrict__ bias, u16t* __restrict__ Qb, u16t* __restrict__ Kb, u16t* __restrict__ Vt)
{
  __shared__ __align__(16) u16t As[16][520];
  __shared__ __align__(16) u16t Cs[16][1024];
  const int r0 = blockIdx.x*16, t = threadIdx.x;
  const int b8 = (r0 >> 9) * 8, pos0 = r0 & 511;
  {
    int row = t>>4, seg = t&15;
    const uint4* src = reinterpret_cast<const uint4*>(hln + (size_t)(r0+row)*512 + seg*32);
    uint4* dst = reinterpret_cast<uint4*>(&As[row][seg*32]);
    dst[0]=src[0]; dst[1]=src[1]; dst[2]=src[2]; dst[3]=src[3];
  }
  __syncthreads();
  const int wv = t>>6, lane = t&63;
  const int frow = lane&15, kgrp = (lane>>4)*8, rbase = (lane>>4)*4;
  for (int nt=0; nt<24; nt++){
    int n0 = (wv*24+nt)*16;
    f32x4 acc = fz4();
    for (int k0=0;k0<512;k0+=32){
      bf16x8 af = *reinterpret_cast<const bf16x8*>(&As[frow][k0+kgrp]);
      bf16x8 bf_ = *reinterpret_cast<const bf16x8*>(Wt + (size_t)(n0+frow)*512 + k0+kgrp);
      acc = MFMA(af,bf_,acc);
    }
    int col = n0 + frow;
    float bs = bias[col];
    if (n0 < 1024){
      #pragma unroll
      for (int r=0;r<4;r++) Cs[rbase+r][col] = bfc(acc[r]+bs);
    } else {
      int cc = col - 1024, dv = cc>>3, hq = cc&7;
      ushort4 u4 = make_ushort4(bfc(acc[0]+bs), bfc(acc[1]+bs), bfc(acc[2]+bs), bfc(acc[3]+bs));
      *reinterpret_cast<ushort4*>(Vt + ((size_t)(b8+hq)*64 + dv)*512 + pos0 + rbase) = u4;
    }
  }
  __syncthreads();
  {
    int pair = t>>1, halfq = t&1;
    int hq = pair>>4, lq = pair&15, d0 = halfq*32;
    int pos = pos0 + lq;
    u16t* qdst = Qb + ((size_t)(b8+hq)*512 + pos)*64 + d0;
    u16t* kdst = Kb + ((size_t)(b8+hq)*512 + pos)*64 + d0;
    #pragma unroll
    for (int v2=0; v2<4; v2++){
      uint4 u, uk;
      u.x  = pk2(Cs[lq][(d0+v2*8+0)*8+hq], Cs[lq][(d0+v2*8+1)*8+hq]);
      u.y  = pk2(Cs[lq][(d0+v2*8+2)*8+hq], Cs[lq][(d0+v2*8+3)*8+hq]);
      u.z  = pk2(Cs[lq][(d0+v2*8+4)*8+hq], Cs[lq][(d0+v2*8+5)*8+hq]);
      u.w  = pk2(Cs[lq][(d0+v2*8+6)*8+hq], Cs[lq][(d0+v2*8+7)*8+hq]);
      uk.x = pk2(Cs[lq][512+(d0+v2*8+0)*8+hq], Cs[lq][512+(d0+v2*8+1)*8+hq]);
      uk.y = pk2(Cs[lq][512+(d0+v2*8+2)*8+hq], Cs[lq][512+(d0+v2*8+3)*8+hq]);
      uk.z = pk2(Cs[lq][512+(d0+v2*8+4)*8+hq], Cs[lq][512+(d0+v2*8+5)*8+hq]);
      uk.w = pk2(Cs[lq][512+(d0+v2*8+6)*8+hq], Cs[lq][512+(d0+v2*8+7)*8+hq]);
      reinterpret_cast<uint4*>(qdst)[v2] = u;
      reinterpret_cast<uint4*>(kdst)[v2] = uk;
    }
  }
}

// ---------------- fused attention: LN(e) -> E,G -> QK^T -> H_hat -> softmax*gate -> PV ----------------
// block = 256 thr (4 waves); each wave owns heads {w, w+4}; block owns (b, 8 l-rows); loops 32 m-tiles of 16.
__global__ __launch_bounds__(256) void kattn(
    const float* __restrict__ e, const float* __restrict__ lng, const float* __restrict__ lnb,
    const float* __restrict__ WE, const float* __restrict__ bE,
    const float* __restrict__ WG, const float* __restrict__ bG,
    const u16t* __restrict__ Qb, const u16t* __restrict__ Kb, const u16t* __restrict__ Vt,
    u16t* __restrict__ Hhat, u16t* __restrict__ Va)
{
  __shared__ __align__(16) u16t Eln[128][72];
  __shared__ float EG[128][17];
  __shared__ __align__(16) u16t Hl[128][8];
  __shared__ __align__(16) u16t Pt[4][2][16][40];
  __shared__ __align__(16) u16t WEGt[16][72];
  __shared__ __align__(16) u16t Vout[8][512];
  __shared__ float lgs[64], lbs[64], bEs[8], bGs[8];

  const int t = threadIdx.x;
  const int b = blockIdx.y, lblk = blockIdx.x;
  const int l0 = lblk*8;
  const int b8 = b*8;

  if (t < 64){ lgs[t] = lng[t]; lbs[t] = lnb[t]; }
  else if (t < 72){ bEs[t-64] = bE[t-64]; }
  else if (t < 80){ bGs[t-72] = bG[t-72]; }
  for (int i=t; i<16*64; i+=256){
    int n = i>>6, k = i&63;
    WEGt[n][k] = bfc(n<8 ? WE[k*8+n] : WG[k*8+(n-8)]);
  }
  __syncthreads();

  const int wv = t>>6, lane = t&63;
  const int frow = lane&15, kgrp = (lane>>4)*8, rbase = (lane>>4)*4;

  bf16x8 qf[2][2];
  #pragma unroll
  for (int s=0;s<2;s++){
    int hq = wv + 4*s;
    #pragma unroll
    for (int kk=0;kk<2;kk++){
      qf[s][kk] = (frow<8)
        ? *reinterpret_cast<const bf16x8*>(Qb + ((size_t)(b8+hq)*512 + l0+frow)*64 + kk*32 + kgrp)
        : bz8();
    }
  }

  f32x4 accV[2][4];
  float Ssum[2][4], Dsum[2][4];
  #pragma unroll
  for (int s=0;s<2;s++){
    #pragma unroll
    for (int d=0;d<4;d++) accV[s][d]=fz4();
    #pragma unroll
    for (int r=0;r<4;r++){ Ssum[s][r]=0.f; Dsum[s][r]=0.f; }
  }

  const int edge1 = t>>1, half1 = t&1, cb1 = half1*32;
  const int le1 = edge1>>4, mm1 = edge1&15;
  const float* ebase = e + ((size_t)((b*512 + l0+le1)*512) + mm1)*64 + cb1;

  for (int mt=0; mt<32; mt++){
    const int m0 = mt*16;
    // phase 1: load e tile, LN over 64 channels (thread pair per edge), -> Eln bf16 (wave-private rows)
    {
      const float4* ep = reinterpret_cast<const float4*>(ebase + (size_t)m0*64);
      float x[32]; float s_=0.f, q_=0.f;
      #pragma unroll
      for (int i=0;i<8;i++){
        float4 v = ep[i];
        x[i*4]=v.x; x[i*4+1]=v.y; x[i*4+2]=v.z; x[i*4+3]=v.w;
        s_ += v.x+v.y+v.z+v.w;
        q_ += v.x*v.x+v.y*v.y+v.z*v.z+v.w*v.w;
      }
      s_ += __shfl_xor(s_,1); q_ += __shfl_xor(q_,1);
      float mean = s_*(1.f/64.f), var = q_*(1.f/64.f)-mean*mean, rs = rsqrtf(var+1e-5f);
      #pragma unroll
      for (int i=0;i<8;i++){
        int c = cb1 + i*4;
        uint2 uv;
        uv.x = pk2(bfc((x[i*4  ]-mean)*rs*lgs[c  ]+lbs[c  ]), bfc((x[i*4+1]-mean)*rs*lgs[c+1]+lbs[c+1]));
        uv.y = pk2(bfc((x[i*4+2]-mean)*rs*lgs[c+2]+lbs[c+2]), bfc((x[i*4+3]-mean)*rs*lgs[c+3]+lbs[c+3]));
        *reinterpret_cast<uint2*>(&Eln[edge1][c]) = uv;
      }
    }
    // phase 2: E||G = Eln @ WEG (wave-private edge tiles), write cross-wave EG
    #pragma unroll
    for (int ti=0; ti<2; ti++){
      int T = wv*2+ti;
      bf16x8 a0 = *reinterpret_cast<const bf16x8*>(&Eln[T*16+frow][kgrp]);
      bf16x8 a1 = *reinterpret_cast<const bf16x8*>(&Eln[T*16+frow][32+kgrp]);
      bf16x8 w0 = *reinterpret_cast<const bf16x8*>(&WEGt[frow][kgrp]);
      bf16x8 w1 = *reinterpret_cast<const bf16x8*>(&WEGt[frow][32+kgrp]);
      f32x4 acc = fz4(); acc = MFMA(a0,w0,acc); acc = MFMA(a1,w1,acc);
      #pragma unroll
      for (int r=0;r<4;r++) EG[T*16+rbase+r][frow] = acc[r];
    }
    __syncthreads();
    // phase 3: per head: QK^T, combine (clip + E, exp, sigmoid gate), PV every 2nd tile
    #pragma unroll
    for (int s=0;s<2;s++){
      int hq = wv + 4*s;
      const u16t* kb = Kb + ((size_t)(b8+hq)*512 + m0)*64;
      bf16x8 kf0 = *reinterpret_cast<const bf16x8*>(kb + frow*64 + kgrp);
      bf16x8 kf1 = *reinterpret_cast<const bf16x8*>(kb + frow*64 + 32 + kgrp);
      f32x4 aq = fz4();
      aq = MFMA(qf[s][0], kf0, aq);
      aq = MFMA(qf[s][1], kf1, aq);
      #pragma unroll
      for (int r=0;r<4;r++){
        int lrow = rbase + r;
        bool valid = (lrow < 8);
        int eidx = (valid ? lrow : 0)*16 + frow;
        float ah = aq[r]*0.125f;
        ah = fminf(fmaxf(ah, -5.f), 5.f);
        float Ev = EG[eidx][hq]   + bEs[hq];
        float Gv = EG[eidx][8+hq] + bGs[hq];
        float Hv = ah + Ev;
        float P = __expf(Hv);
        float g = 1.f/(1.f+__expf(-Gv));
        if (!valid){ P=0.f; g=0.f; }
        Ssum[s][r] += P; Dsum[s][r] += g;
        if (valid) Hl[eidx][hq] = bfc(Hv);
        Pt[wv][s][lrow][(mt&1)*16 + frow] = bfc(P*g);
      }
      if (mt & 1){
        const int mp = m0 - 16;
        bf16x8 pf = *reinterpret_cast<const bf16x8*>(&Pt[wv][s][frow][kgrp]);
        const u16t* vb = Vt + (size_t)(b8+hq)*64*512 + mp;
        #pragma unroll
        for (int db=0; db<4; db++){
          bf16x8 vf = *reinterpret_cast<const bf16x8*>(vb + (size_t)(db*16+frow)*512 + kgrp);
          accV[s][db] = MFMA(pf, vf, accV[s][db]);
        }
      }
    }
    __syncthreads();
    // phase 4: coalesced H_hat writeout
    if (t < 128){
      uint4 hv = *reinterpret_cast<const uint4*>(&Hl[t][0]);
      int le = t>>4, mm = t&15;
      *reinterpret_cast<uint4*>(Hhat + ((size_t)((b*512+l0+le)*512) + m0+mm)*8) = hv;
    }
    __syncthreads();
  }

  // epilogue: softmax denom + degree scale, write V_att
  float scale_[2][4];
  #pragma unroll
  for (int s=0;s<2;s++){
    #pragma unroll
    for (int r=0;r<4;r++){
      float sv = Ssum[s][r], dv = Dsum[s][r];
      #pragma unroll
      for (int msk=1; msk<16; msk<<=1){ sv += __shfl_xor(sv, msk); dv += __shfl_xor(dv, msk); }
      scale_[s][r] = log1pf(dv) / sv;
    }
  }
  #pragma unroll
  for (int s=0;s<2;s++){
    int hq = wv + 4*s;
    #pragma unroll
    for (int db=0;db<4;db++){
      #pragma unroll
      for (int r=0;r<4;r++){
        int lrow = rbase + r;
        if (lrow < 8) Vout[lrow][(db*16+frow)*8 + hq] = bfc(accV[s][db][r] * scale_[s][r]);
      }
    }
  }
  __syncthreads();
  {
    int lr = t>>5, seg = t&31;
    const uint4* vsrc = reinterpret_cast<const uint4*>(&Vout[lr][seg*16]);
    uint4 v0 = vsrc[0], v1 = vsrc[1];
    uint4* vd = reinterpret_cast<uint4*>(Va + ((size_t)(b*512 + l0 + lr))*512 + seg*16);
    vd[0]=v0; vd[1]=v1;
  }
}

// ---------------- edge FFN: e1 = Hhat@WOe + bOe + e; LN; elu(ef@We1+b)@We2 + b + e1 ----------------
// barrier-free main loop: each wave owns 32 edges (2 MFMA row-tiles) end to end.
__global__ __launch_bounds__(256) void kedge(
    const float* __restrict__ e, const u16t* __restrict__ Hhat,
    const float* __restrict__ WOe, const float* __restrict__ bOe,
    const float* __restrict__ lng, const float* __restrict__ lnb,
    const float* __restrict__ We1, const float* __restrict__ be1,
    const float* __restrict__ We2, const float* __restrict__ be2,
    float* __restrict__ eout)
{
  __shared__ __align__(16) u16t Ef[128][72];   // e_f, then reused as X1
  __shared__ __align__(16) u16t E1[128][72];   // e1 residual (bf16)
  __shared__ __align__(16) u16t We1t[64][72];
  __shared__ __align__(16) u16t We2t[64][72];
  __shared__ float WOes[8][64];
  __shared__ float bOes[64], be1s[64], be2s[64], lgs[64], lbs[64];

  const int t = threadIdx.x;
  for (int i=t; i<4096; i+=256){
    int n=i>>6, k=i&63;
    We1t[n][k] = bfc(We1[k*64+n]);
    We2t[n][k] = bfc(We2[k*64+n]);
  }
  for (int i=t;i<512;i+=256) WOes[i>>6][i&63] = WOe[i];
  if (t<64){ bOes[t]=bOe[t]; be1s[t]=be1[t]; be2s[t]=be2[t]; lgs[t]=lng[t]; lbs[t]=lnb[t]; }
  __syncthreads();

  const int wv=t>>6, lane=t&63;
  const int frow=lane&15, kgrp=(lane>>4)*8, rbase=(lane>>4)*4;

  for (int it=0; it<4; it++){
    const size_t e0 = ((size_t)blockIdx.x*4 + it)*128;
    // P1: e1 + LN -> Ef/E1 (wave-private rows wv*32..wv*32+31)
    {
      const int el = wv*32 + (lane>>1);
      const int cb = (lane&1)*32;
      const float4* ep = reinterpret_cast<const float4*>(e + (e0+el)*64 + cb);
      uint4 hv = *reinterpret_cast<const uint4*>(Hhat + (e0+el)*8);
      float hf_[8]; unpack8(hv, hf_);
      float e1v[32];
      #pragma unroll
      for (int i=0;i<8;i++){
        float4 v = ep[i];
        e1v[i*4]=v.x+bOes[cb+i*4]; e1v[i*4+1]=v.y+bOes[cb+i*4+1];
        e1v[i*4+2]=v.z+bOes[cb+i*4+2]; e1v[i*4+3]=v.w+bOes[cb+i*4+3];
      }
      #pragma unroll
      for (int hq=0;hq<8;hq++){
        float hvv = hf_[hq];
        #pragma unroll
        for (int i=0;i<32;i++) e1v[i] += hvv * WOes[hq][cb+i];
      }
      float s_=0.f,q_=0.f;
      #pragma unroll
      for (int i=0;i<32;i++){ s_+=e1v[i]; q_+=e1v[i]*e1v[i]; }
      s_ += __shfl_xor(s_,1); q_ += __shfl_xor(q_,1);
      float mean = s_*(1.f/64.f), var = q_*(1.f/64.f)-mean*mean, rs = rsqrtf(var+1e-5f);
      #pragma unroll
      for (int i=0;i<8;i++){
        int c = cb+i*4;
        uint2 uf, ue;
        uf.x = pk2(bfc((e1v[i*4  ]-mean)*rs*lgs[c  ]+lbs[c  ]), bfc((e1v[i*4+1]-mean)*rs*lgs[c+1]+lbs[c+1]));
        uf.y = pk2(bfc((e1v[i*4+2]-mean)*rs*lgs[c+2]+lbs[c+2]), bfc((e1v[i*4+3]-mean)*rs*lgs[c+3]+lbs[c+3]));
        ue.x = pk2(bfc(e1v[i*4  ]), bfc(e1v[i*4+1]));
        ue.y = pk2(bfc(e1v[i*4+2]), bfc(e1v[i*4+3]));
        *reinterpret_cast<uint2*>(&Ef[el][c]) = uf;
        *reinterpret_cast<uint2*>(&E1[el][c]) = ue;
      }
    }
    // P2: layer1 MFMAs (read Ef) -> elu -> write X1 over Ef (same wave rows)
    f32x4 acc1[8];
    #pragma unroll
    for (int ui=0; ui<8; ui++){
      int T = 2*wv + (ui>>2), nb = ui&3;
      bf16x8 a0 = *reinterpret_cast<const bf16x8*>(&Ef[T*16+frow][kgrp]);
      bf16x8 a1 = *reinterpret_cast<const bf16x8*>(&Ef[T*16+frow][32+kgrp]);
      bf16x8 w0 = *reinterpret_cast<const bf16x8*>(&We1t[nb*16+frow][kgrp]);
      bf16x8 w1 = *reinterpret_cast<const bf16x8*>(&We1t[nb*16+frow][32+kgrp]);
      f32x4 a_ = fz4(); a_ = MFMA(a0,w0,a_); a_ = MFMA(a1,w1,a_);
      acc1[ui] = a_;
    }
    #pragma unroll
    for (int ui=0; ui<8; ui++){
      int T = 2*wv + (ui>>2), nb = ui&3;
      int n = nb*16 + frow;
      #pragma unroll
      for (int r=0;r<4;r++){
        float xv = acc1[ui][r] + be1s[n];
        xv = xv>0.f ? xv : expm1f(xv);
        Ef[T*16+rbase+r][n] = bfc(xv);
      }
    }
    // P3: layer2 MFMAs + residual + store
    #pragma unroll
    for (int ui=0; ui<8; ui++){
      int T = 2*wv + (ui>>2), nb = ui&3;
      bf16x8 a0 = *reinterpret_cast<const bf16x8*>(&Ef[T*16+frow][kgrp]);
      bf16x8 a1 = *reinterpret_cast<const bf16x8*>(&Ef[T*16+frow][32+kgrp]);
      bf16x8 w0 = *reinterpret_cast<const bf16x8*>(&We2t[nb*16+frow][kgrp]);
      bf16x8 w1 = *reinterpret_cast<const bf16x8*>(&We2t[nb*16+frow][32+kgrp]);
      f32x4 a_ = fz4(); a_ = MFMA(a0,w0,a_); a_ = MFMA(a1,w1,a_);
      int n = nb*16 + frow;
      #pragma unroll
      for (int r=0;r<4;r++){
        int el = T*16 + rbase + r;
        eout[(e0+el)*64 + n] = a_[r] + be2s[n] + flc(E1[el][n]);
      }
    }
  }
}

// ---------------- generic 16-row GEMM: out = A@Bt^T + bias (+res) (elu opt) ----------------
__global__ __launch_bounds__(256) void kgemm(const u16t* __restrict__ A, const u16t* __restrict__ Bt,
    const float* __restrict__ bias, const float* __restrict__ res,
    float* __restrict__ outf, u16t* __restrict__ outb, int N, int K, int do_elu)
{
  __shared__ __align__(16) u16t As[16][1032];
  const int r0 = blockIdx.x*16, t = threadIdx.x;
  {
    int row = t>>4, seg = t&15, cnt = K>>4;
    const uint4* src = reinterpret_cast<const uint4*>(A + (size_t)(r0+row)*K + seg*cnt);
    uint4* dst = reinterpret_cast<uint4*>(&As[row][seg*cnt]);
    for (int i=0;i<(cnt>>3);i++) dst[i] = src[i];
  }
  __syncthreads();
  const int wv = t>>6, lane = t&63;
  const int frow = lane&15, kgrp = (lane>>4)*8, rbase = (lane>>4)*4;
  const int ntiles = N>>6;
  for (int nt=0; nt<ntiles; nt++){
    int n0 = (nt*4 + wv)*16;
    f32x4 acc = fz4();
    for (int k0=0;k0<K;k0+=32){
      bf16x8 af = *reinterpret_cast<const bf16x8*>(&As[frow][k0+kgrp]);
      bf16x8 bf_ = *reinterpret_cast<const bf16x8*>(Bt + (size_t)(n0+frow)*K + k0+kgrp);
      acc = MFMA(af,bf_,acc);
    }
    int col = n0 + frow;
    float bs = bias[col];
    #pragma unroll
    for (int r=0;r<4;r++){
      size_t row = (size_t)(r0 + rbase + r);
      float v = acc[r] + bs;
      if (do_elu) v = v>0.f ? v : expm1f(v);
      if (res)  v += res[row*N + col];
      if (outf) outf[row*N + col] = v;
      if (outb) outb[row*N + col] = bfc(v);
    }
  }
}

extern "C" void kernel_launch(void* const* d_in, const int* in_sizes, int n_in,
                              void* d_out, int out_size, void* d_ws, size_t ws_size,
                              hipStream_t stream)
{
  (void)in_sizes; (void)n_in; (void)out_size; (void)ws_size;
  const float* h      = (const float*)d_in[0];
  const float* e      = (const float*)d_in[1];
  const float* ln_h_g = (const float*)d_in[2];
  const float* ln_h_b = (const float*)d_in[3];
  const float* ln_e_g = (const float*)d_in[4];
  const float* ln_e_b = (const float*)d_in[5];
  const float* W_QKV  = (const float*)d_in[6];
  const float* b_QKV  = (const float*)d_in[7];
  const float* W_E    = (const float*)d_in[8];
  const float* b_E    = (const float*)d_in[9];
  const float* W_G    = (const float*)d_in[10];
  const float* b_G    = (const float*)d_in[11];
  const float* W_Oh   = (const float*)d_in[12];
  const float* b_Oh   = (const float*)d_in[13];
  const float* f_ln_h_g = (const float*)d_in[14];
  const float* f_ln_h_b = (const float*)d_in[15];
  const float* W_h1   = (const float*)d_in[16];
  const float* b_h1   = (const float*)d_in[17];
  const float* W_h2   = (const float*)d_in[18];
  const float* b_h2   = (const float*)d_in[19];
  const float* W_Oe   = (const float*)d_in[20];
  const float* b_Oe   = (const float*)d_in[21];
  const float* f_ln_e_g = (const float*)d_in[22];
  const float* f_ln_e_b = (const float*)d_in[23];
  const float* W_e1   = (const float*)d_in[24];
  const float* b_e1   = (const float*)d_in[25];
  const float* W_e2   = (const float*)d_in[26];
  const float* b_e2   = (const float*)d_in[27];

  float* out   = (float*)d_out;
  float* h_out = out;
  float* e_out = out + (size_t)4*512*512;

  char* w = (char*)d_ws;
  size_t off = 0;
  auto alloc = [&](size_t bytes)->char*{ char* p = w + off; off += (bytes + 255) & ~(size_t)255; return p; };
  u16t* hln   = (u16t*)alloc(2048ull*512*2);
  u16t* WtQKV = (u16t*)alloc(1536ull*512*2);
  u16t* WtOh  = (u16t*)alloc(512ull*512*2);
  u16t* WtH1  = (u16t*)alloc(1024ull*512*2);
  u16t* WtH2  = (u16t*)alloc(512ull*1024*2);
  u16t* Qb    = (u16t*)alloc(4ull*8*512*64*2);
  u16t* Kb    = (u16t*)alloc(4ull*8*512*64*2);
  u16t* Vt    = (u16t*)alloc(4ull*8*64*512*2);
  u16t* Hh    = (u16t*)alloc(4ull*512*512*8*2);
  u16t* Va    = (u16t*)alloc(2048ull*512*2);
  float* h1   = (float*)alloc(2048ull*512*4);
  u16t* hfb   = (u16t*)alloc(2048ull*512*2);
  u16t* U     = (u16t*)alloc(2048ull*1024*2);

  kwT<<<(1536*512+255)/256, 256, 0, stream>>>(W_QKV, WtQKV, 1536, 512);
  kwT<<<(512*512+255)/256,  256, 0, stream>>>(W_Oh,  WtOh,  512,  512);
  kwT<<<(1024*512+255)/256, 256, 0, stream>>>(W_h1,  WtH1,  1024, 512);
  kwT<<<(512*1024+255)/256, 256, 0, stream>>>(W_h2,  WtH2,  512,  1024);
  kln<<<512, 256, 0, stream>>>(h, ln_h_g, ln_h_b, hln);
  kqkv<<<128, 256, 0, stream>>>(hln, WtQKV, b_QKV, Qb, Kb, Vt);
  kattn<<<dim3(64,4), 256, 0, stream>>>(e, ln_e_g, ln_e_b, W_E, b_E, W_G, b_G, Qb, Kb, Vt, Hh, Va);
  kedge<<<2048, 256, 0, stream>>>(e, Hh, W_Oe, b_Oe, f_ln_e_g, f_ln_e_b, W_e1, b_e1, W_e2, b_e2, e_out);
  kgemm<<<128, 256, 0, stream>>>(Va, WtOh, b_Oh, h, h1, nullptr, 512, 512, 0);
  kln<<<512, 256, 0, stream>>>(h1, f_ln_h_g, f_ln_h_b, hfb);
  kgemm<<<128, 256, 0, stream>>>(hfb, WtH1, b_h1, nullptr, nullptr, U, 1024, 512, 1);
  kgemm<<<128, 256, 0, stream>>>(U, WtH2, b_h2, h1, h_out, nullptr, 512, 1024, 0);
}